// Round 1
// baseline (45001.538 us; speedup 1.0000x reference)
//
#include <hip/hip_runtime.h>
#include <math.h>

#define B 128
#define T 512
#define D 512
#define H 512

// d_out layout (floats): out (B,T,2H) | c_out (B,T,2H) | out_last (B,2H) | c_last (B,2H)
// ws layout (floats): hbuf: 8 slots of B*H  (cell*2+parity), cbuf: 8 slots of B*H
// cells: 0 = 0f, 1 = 0b, 2 = 1f, 3 = 1b  (matches d_in dict order)

struct Params {
  const float* x;
  const float* w_ih[4];
  const float* w_hh[4];
  const float* b_ih[4];
  const float* b_hh[4];
  float* hbuf;
  float* cbuf;
  float* out;
  int s;   // wavefront step: layer0 runs t=s, layer1 runs t=s-1
};

__device__ __forceinline__ float sigmoidf_(float v) {
  return 1.0f / (1.0f + __expf(-v));
}

__global__ void init_zero_kernel(float* ptr, int n) {
  int i = blockIdx.x * blockDim.x + threadIdx.x;
  int stride = gridDim.x * blockDim.x;
  for (; i < n; i += stride) ptr[i] = 0.0f;
}

// 256 blocks x 256 threads. Block tile: M=64 (batch half) x N=64 (16 h-dims x 4 gates), K=512+512.
__global__ __launch_bounds__(256) void lstm_step_kernel(Params p) {
  const int blk   = blockIdx.x;
  const int layer = blk >> 7;                 // 0 or 1
  const int t     = (layer == 0) ? p.s : p.s - 1;
  if (t < 0 || t >= T) return;
  const int lb    = blk & 127;
  const int dir   = lb >> 6;                  // 0=f, 1=b
  const int sub   = lb & 63;
  const int dgrp  = sub >> 1;                 // 0..31 -> h-dim group of 16
  const int mhalf = sub & 1;                  // batch half
  const int cell  = layer * 2 + dir;          // 0:0f 1:0b 2:1f 3:1b
  const int d0    = dgrp * 16;
  const int m0    = mhalf * 64;
  const int tid   = threadIdx.x;
  const int tx    = tid & 15;                 // n-group: n = tx*4+ni
  const int ty    = tid >> 4;                 // m-group: m = ty*4+mi

  const int tpar = t & 1;        // parity written at step t
  const int ppar = tpar ^ 1;     // parity of t-1 state
  const int flip = (cell == 1);  // 0b: x features reversed -> flip w_ih columns

  __shared__ float sA[64][68];   // activations [m][k]  (68: float4-aligned rows, low bank conflict)
  __shared__ float sW[64][68];   // weights     [n][k]

  float acc[4][4];
  // init with biases (b_ih + b_hh), same for every batch row
  #pragma unroll
  for (int ni = 0; ni < 4; ni++) {
    int n   = tx * 4 + ni;
    int row = d0 + (n & 15) + (n >> 4) * H;   // gate row in [0,4H)
    float bias = p.b_ih[cell][row] + p.b_hh[cell][row];
    #pragma unroll
    for (int mi = 0; mi < 4; mi++) acc[mi][ni] = bias;
  }

  for (int ph = 0; ph < 2; ph++) {
    const float* act;       // element = act[(m0+r)*rstride + k]
    size_t rstride;
    const float* w;
    if (ph == 0) {
      if (layer == 0) { act = p.x + (size_t)t * D; rstride = (size_t)T * D; }
      else            { act = p.hbuf + (size_t)(dir * 2 + tpar) * B * H; rstride = H; }
      w = p.w_ih[cell];
    } else {
      act = p.hbuf + (size_t)(cell * 2 + ppar) * B * H; rstride = H;
      w = p.w_hh[cell];
    }

    for (int kc = 0; kc < 512; kc += 64) {
      __syncthreads();   // previous chunk's compute must finish before overwrite
      // stage activations: 64 rows x 64 cols
      #pragma unroll
      for (int q = 0; q < 4; q++) {
        int idx = tid + q * 256;
        int r   = idx >> 4;
        int c4  = idx & 15;
        float4 v = *(const float4*)(act + (size_t)(m0 + r) * rstride + kc + c4 * 4);
        sA[r][c4*4+0] = v.x; sA[r][c4*4+1] = v.y; sA[r][c4*4+2] = v.z; sA[r][c4*4+3] = v.w;
      }
      // stage weights: 64 gate-rows x 64 cols
      if (ph == 0 && flip) {
        #pragma unroll
        for (int q = 0; q < 4; q++) {
          int idx = tid + q * 256;
          int r   = idx >> 4;
          int c4  = idx & 15;
          int row = d0 + (r & 15) + (r >> 4) * H;
          #pragma unroll
          for (int j = 0; j < 4; j++) {
            int k = kc + c4 * 4 + j;
            sW[r][c4*4+j] = w[(size_t)row * D + (D - 1 - k)];
          }
        }
      } else {
        #pragma unroll
        for (int q = 0; q < 4; q++) {
          int idx = tid + q * 256;
          int r   = idx >> 4;
          int c4  = idx & 15;
          int row = d0 + (r & 15) + (r >> 4) * H;
          float4 v = *(const float4*)(w + (size_t)row * 512 + kc + c4 * 4);
          sW[r][c4*4+0] = v.x; sW[r][c4*4+1] = v.y; sW[r][c4*4+2] = v.z; sW[r][c4*4+3] = v.w;
        }
      }
      __syncthreads();
      // 64x64x64 MACs per block: 4m x 4n register tile, dot-4 per step
      #pragma unroll
      for (int kk = 0; kk < 64; kk += 4) {
        float4 av[4], wv[4];
        #pragma unroll
        for (int mi = 0; mi < 4; mi++) av[mi] = *(const float4*)&sA[ty*4+mi][kk];
        #pragma unroll
        for (int ni = 0; ni < 4; ni++) wv[ni] = *(const float4*)&sW[tx*4+ni][kk];
        #pragma unroll
        for (int mi = 0; mi < 4; mi++)
          #pragma unroll
          for (int ni = 0; ni < 4; ni++)
            acc[mi][ni] += av[mi].x * wv[ni].x + av[mi].y * wv[ni].y
                         + av[mi].z * wv[ni].z + av[mi].w * wv[ni].w;
      }
    }
  }

  // gates -> LDS (as [n][m]) so each thread can gather i/f/g/o for its (b,d) pairs
  __syncthreads();
  #pragma unroll
  for (int ni = 0; ni < 4; ni++)
    #pragma unroll
    for (int mi = 0; mi < 4; mi++)
      sA[tx*4+ni][ty*4+mi] = acc[mi][ni];
  __syncthreads();

  const size_t OUT1 = (size_t)B * T * 2 * H;          // c_out
  const size_t OUT2 = 2 * OUT1;                       // out[:, -1]
  const size_t OUT3 = OUT2 + (size_t)B * 2 * H;       // c_out[:, -1]

  #pragma unroll
  for (int q = 0; q < 4; q++) {
    int idx = tid + q * 256;
    int mb  = idx & 63;
    int j   = idx >> 6;      // 0..15
    float gi = sigmoidf_(sA[j][mb]);
    float gf = sigmoidf_(sA[16 + j][mb]);
    float gg = tanhf(sA[32 + j][mb]);
    float go = sigmoidf_(sA[48 + j][mb]);
    int b = m0 + mb;
    int d = d0 + j;
    size_t hidx = (size_t)b * H + d;
    float cprev = p.cbuf[(size_t)(cell * 2 + ppar) * B * H + hidx];
    float c2 = gf * cprev + gi * gg;
    float h2 = go * tanhf(c2);
    p.hbuf[(size_t)(cell * 2 + tpar) * B * H + hidx] = h2;
    p.cbuf[(size_t)(cell * 2 + tpar) * B * H + hidx] = c2;
    if (layer == 1) {
      size_t o = (size_t)b * (T * 2 * H) + (size_t)t * (2 * H) + dir * H + d;
      p.out[o]        = h2;
      p.out[OUT1 + o] = c2;
      if (t == T - 1) {
        size_t o2 = (size_t)b * (2 * H) + dir * H + d;
        p.out[OUT2 + o2] = h2;
        p.out[OUT3 + o2] = c2;
      }
    }
  }
}

extern "C" void kernel_launch(void* const* d_in, const int* in_sizes, int n_in,
                              void* d_out, int out_size, void* d_ws, size_t ws_size,
                              hipStream_t stream) {
  Params p;
  p.x = (const float*)d_in[0];
  for (int c = 0; c < 4; c++) {
    p.w_ih[c] = (const float*)d_in[1 + c * 4 + 0];
    p.w_hh[c] = (const float*)d_in[1 + c * 4 + 1];
    p.b_ih[c] = (const float*)d_in[1 + c * 4 + 2];
    p.b_hh[c] = (const float*)d_in[1 + c * 4 + 3];
  }
  p.hbuf = (float*)d_ws;
  p.cbuf = (float*)d_ws + (size_t)8 * B * H;
  p.out  = (float*)d_out;

  // zero all 16 h/c state slots (ws is poisoned before every call)
  init_zero_kernel<<<256, 256, 0, stream>>>(p.hbuf, 16 * B * H);

  // wavefront over steps: kernel s computes layer0@t=s and layer1@t=s-1
  for (int s = 0; s <= T; s++) {
    p.s = s;
    lstm_step_kernel<<<256, 256, 0, stream>>>(p);
  }
}